// Round 3
// baseline (120.802 us; speedup 1.0000x reference)
//
#include <hip/hip_runtime.h>

static constexpr int E = 256;
static constexpr int S = 4096;

typedef __attribute__((ext_vector_type(8))) short short8v;   // 8 bf16 (4 VGPRs)
typedef __attribute__((ext_vector_type(4))) float f32x4;     // 4 fp32 acc

static __device__ __forceinline__ unsigned short f2bf(float f) {
    union { float f; unsigned u; } v; v.f = f;
    unsigned r = v.u + 0x7fffu + ((v.u >> 16) & 1u);   // RNE
    return (unsigned short)(r >> 16);
}

static __device__ __forceinline__ f32x4 mfma16(short8v a, short8v b, f32x4 c) {
    return __builtin_amdgcn_mfma_f32_16x16x32_bf16(a, b, c, 0, 0, 0);
}

// 32x32 output tile, 1 wave. A rows at pa0 (row=lr, +16 for second half),
// B rows at pb0. acc[qr*2+qc]: quadrant rows +qr*16, cols +qc*16.
static __device__ __forceinline__ void gemm_tile32(
    const unsigned short* pa0, const unsigned short* pb0,
    long sA, long sB, int K, f32x4 acc[4])
{
    const unsigned short* pa1 = pa0 + 16 * sA;
    const unsigned short* pb1 = pb0 + 16 * sB;
    #pragma unroll 4
    for (int k = 0; k < K; k += 32) {
        const short8v a0 = *(const short8v*)(pa0 + k);
        const short8v a1 = *(const short8v*)(pa1 + k);
        const short8v b0 = *(const short8v*)(pb0 + k);
        const short8v b1 = *(const short8v*)(pb1 + k);
        acc[0] = mfma16(a0, b0, acc[0]);
        acc[1] = mfma16(a0, b1, acc[1]);
        acc[2] = mfma16(a1, b0, acc[2]);
        acc[3] = mfma16(a1, b1, acc[3]);
    }
}

// ---------------------------------------------------------------------------
// x fp32 -> Xb bf16 [16384][256] and XT bf16 [b][256][4096]  (blockIdx.y<256)
// W* fp32 -> Wrow[wi] bf16 row-major and Wtr[wi] bf16 transposed (y>=256)
__global__ __launch_bounds__(256) void convert_kernel(
    const float* __restrict__ X,
    const float* __restrict__ Wq, const float* __restrict__ Wk,
    const float* __restrict__ Wv, const float* __restrict__ Wo,
    unsigned short* __restrict__ Xb, unsigned short* __restrict__ XT,
    unsigned short* __restrict__ Wrow, unsigned short* __restrict__ Wtr)
{
    __shared__ unsigned short Ls[64][66];
    const int t  = threadIdx.x;
    const int e0 = blockIdx.x * 64;
    const int lr = t >> 2;          // local row
    const int lc = (t & 3) * 16;    // local col segment
    const float* src;
    unsigned short* drow;
    unsigned short* dtr;
    if (blockIdx.y < 256) {
        const int s0 = blockIdx.y * 64;
        src  = X  + (long)(s0 + lr) * E + e0 + lc;
        drow = Xb + (long)(s0 + lr) * E + e0 + lc;
        const int b = s0 >> 12, sl = s0 & 4095;
        dtr = XT + ((long)(b * E + e0 + lr)) * S + sl + lc;
    } else {
        const int wy = blockIdx.y - 256;
        const int wi = wy >> 2, rt = wy & 3;
        const float* W = (wi == 0) ? Wq : (wi == 1) ? Wk : (wi == 2) ? Wv : Wo;
        src  = W + (long)(rt * 64 + lr) * E + e0 + lc;
        drow = Wrow + (long)wi * 65536 + (long)(rt * 64 + lr) * E + e0 + lc;
        dtr  = Wtr  + (long)wi * 65536 + (long)(e0 + lr) * E + rt * 64 + lc;
    }
    short8v v0, v1;
    #pragma unroll
    for (int q = 0; q < 4; ++q) {
        const float4 v = *(const float4*)(src + q * 4);
        const unsigned short b0 = f2bf(v.x), b1 = f2bf(v.y), b2 = f2bf(v.z), b3 = f2bf(v.w);
        Ls[lc + q*4 + 0][lr] = b0; Ls[lc + q*4 + 1][lr] = b1;
        Ls[lc + q*4 + 2][lr] = b2; Ls[lc + q*4 + 3][lr] = b3;
        if (q < 2) { v0[q*4+0]=(short)b0; v0[q*4+1]=(short)b1; v0[q*4+2]=(short)b2; v0[q*4+3]=(short)b3; }
        else { v1[(q-2)*4+0]=(short)b0; v1[(q-2)*4+1]=(short)b1; v1[(q-2)*4+2]=(short)b2; v1[(q-2)*4+3]=(short)b3; }
    }
    *(short8v*)(drow)     = v0;
    *(short8v*)(drow + 8) = v1;
    __syncthreads();
    short8v w0, w1;
    #pragma unroll
    for (int j = 0; j < 8; ++j) { w0[j] = (short)Ls[lr][lc + j]; w1[j] = (short)Ls[lr][lc + 8 + j]; }
    *(short8v*)(dtr)     = w0;
    *(short8v*)(dtr + 8) = w1;
}

// ---------------------------------------------------------------------------
// blockIdx.y<4 : G_b = x_b^T x_b  (bf16 out, symmetric)
// blockIdx.y==4: P = Wq^T Wk      (A=WqT, B=WkT)
// blockIdx.y==5: Rt = Wo Wv       (A=Wo row, B=WvT)   [Rt = R~^T]
__global__ __launch_bounds__(256) void gram_pr_kernel(
    const unsigned short* __restrict__ XT, const unsigned short* __restrict__ Wrow,
    const unsigned short* __restrict__ Wtr,
    unsigned short* __restrict__ G, unsigned short* __restrict__ P,
    unsigned short* __restrict__ Rt)
{
    const int lane = threadIdx.x & 63;
    const int lr = lane & 15, lg = lane >> 4;
    const int w  = blockIdx.x * 4 + (threadIdx.x >> 6);
    const int ti = w >> 3, tj = w & 7;
    const int by = blockIdx.y;
    f32x4 acc[4] = {};
    unsigned short* out;
    if (by < 4) {
        const unsigned short* base = XT + (long)by * E * S + lg * 8;
        gemm_tile32(base + (long)(ti * 32 + lr) * S,
                    base + (long)(tj * 32 + lr) * S, S, S, S, acc);
        out = G + ((long)by << 16);
    } else {
        const unsigned short* A = (by == 4) ? Wtr            : (Wrow + 3 * 65536);
        const unsigned short* B = (by == 4) ? (Wtr + 65536)  : (Wtr + 2 * 65536);
        gemm_tile32(A + (long)(ti * 32 + lr) * E + lg * 8,
                    B + (long)(tj * 32 + lr) * E + lg * 8, E, E, E, acc);
        out = (by == 4) ? P : Rt;
    }
    #pragma unroll
    for (int q = 0; q < 4; ++q) {
        const int qr = q >> 1, qc = q & 1;
        #pragma unroll
        for (int r = 0; r < 4; ++r) {
            const int row = ti * 32 + qr * 16 + lg * 4 + r;
            const int col = tj * 32 + qc * 16 + lr;
            out[row * E + col] = f2bf(acc[q][r]);
        }
    }
}

// ---------------------------------------------------------------------------
// Per (band i0, batch b): Tband = P[i0:i0+64,:] @ G_b  -> LDS bf16
// then MT[b][g][i0:i0+64] = 1e-11 * (Rt @ Tband^T)   (Mt[g,e] = sum_c Rt[g,c] T[e,c])
__global__ __launch_bounds__(1024) void tm_kernel(
    const unsigned short* __restrict__ P, const unsigned short* __restrict__ G,
    const unsigned short* __restrict__ Rt, unsigned short* __restrict__ MT)
{
    __shared__ unsigned short Ts[64][264];   // 528B row stride -> ~2-way on b128
    const int b  = blockIdx.y;
    const int i0 = blockIdx.x * 64;
    const int widx = threadIdx.x >> 6;
    const int lane = threadIdx.x & 63;
    const int lr = lane & 15, lg = lane >> 4;
    {   // stage 1: 2 row-tiles x 8 col-tiles
        const int tr = widx >> 3, tc = widx & 7;
        f32x4 acc[4] = {};
        gemm_tile32(P + (long)(i0 + tr * 32 + lr) * E + lg * 8,
                    G + ((long)b << 16) + (long)(tc * 32 + lr) * E + lg * 8,
                    E, E, E, acc);
        #pragma unroll
        for (int q = 0; q < 4; ++q) {
            const int qr = q >> 1, qc = q & 1;
            #pragma unroll
            for (int r = 0; r < 4; ++r)
                Ts[tr * 32 + qr * 16 + lg * 4 + r][tc * 32 + qc * 16 + lr] = f2bf(acc[q][r]);
        }
    }
    __syncthreads();
    {   // stage 2: 8 g-tiles x 2 e-tiles
        const int tg = widx >> 1, te = widx & 1;
        f32x4 acc[4] = {};
        gemm_tile32(Rt + (long)(tg * 32 + lr) * E + lg * 8,
                    &Ts[te * 32 + lr][lg * 8], E, 264, E, acc);
        unsigned short* out = MT + ((long)b << 16);
        #pragma unroll
        for (int q = 0; q < 4; ++q) {
            const int qr = q >> 1, qc = q & 1;
            #pragma unroll
            for (int r = 0; r < 4; ++r) {
                const int g = tg * 32 + qr * 16 + lg * 4 + r;
                const int e = te * 32 + qc * 16 + lr;
                out[g * E + i0 + e] = f2bf(acc[q][r] * 1e-11f);
            }
        }
    }
}

// ---------------------------------------------------------------------------
// out = Xb @ M_b. 1 wave = 32 rows x 64 cols; block = 4 waves = 128 rows.
__global__ __launch_bounds__(256) void final_kernel(
    const unsigned short* __restrict__ Xb, const unsigned short* __restrict__ MT,
    float* __restrict__ Out)
{
    const int s0 = blockIdx.y * 128 + (threadIdx.x >> 6) * 32;
    const int g0 = blockIdx.x * 64;
    const int b  = s0 >> 12;
    const int lane = threadIdx.x & 63;
    const int lr = lane & 15, lg = lane >> 4;
    const unsigned short* pa0 = Xb + (long)(s0 + lr) * E + lg * 8;
    const unsigned short* pa1 = pa0 + 16 * E;
    const unsigned short* pb  = MT + ((long)b * E + g0 + lr) * E + lg * 8;
    f32x4 acc[2][4] = {};
    #pragma unroll
    for (int k = 0; k < E; k += 32) {
        const short8v a0 = *(const short8v*)(pa0 + k);
        const short8v a1 = *(const short8v*)(pa1 + k);
        #pragma unroll
        for (int ni = 0; ni < 4; ++ni) {
            const short8v bf = *(const short8v*)(pb + (long)ni * 16 * E + k);
            acc[0][ni] = mfma16(a0, bf, acc[0][ni]);
            acc[1][ni] = mfma16(a1, bf, acc[1][ni]);
        }
    }
    #pragma unroll
    for (int mi = 0; mi < 2; ++mi)
        #pragma unroll
        for (int r = 0; r < 4; ++r) {
            float* row = Out + (long)(s0 + mi * 16 + lg * 4 + r) * E + g0 + lr;
            #pragma unroll
            for (int ni = 0; ni < 4; ++ni) row[ni * 16] = acc[mi][ni][r];
        }
}

// ---------------------------------------------------------------------------
extern "C" void kernel_launch(void* const* d_in, const int* in_sizes, int n_in,
                              void* d_out, int out_size, void* d_ws, size_t ws_size,
                              hipStream_t stream)
{
    const float* x  = (const float*)d_in[0];
    const float* Wq = (const float*)d_in[1];
    const float* Wk = (const float*)d_in[2];
    const float* Wv = (const float*)d_in[3];
    const float* Wo = (const float*)d_in[4];
    float* out = (float*)d_out;

    char* ws = (char*)d_ws;
    unsigned short* Xb   = (unsigned short*)(ws);                 // 8.39 MB
    unsigned short* XT   = (unsigned short*)(ws + 8388608);       // 8.39 MB
    unsigned short* Wrow = (unsigned short*)(ws + 16777216);      // 0.52 MB
    unsigned short* Wtr  = (unsigned short*)(ws + 17301504);      // 0.52 MB
    unsigned short* G    = (unsigned short*)(ws + 17825792);      // 0.52 MB
    unsigned short* P    = (unsigned short*)(ws + 18350080);      // 0.13 MB
    unsigned short* Rt   = (unsigned short*)(ws + 18481152);      // 0.13 MB
    unsigned short* MT   = (unsigned short*)(ws + 18612224);      // 0.52 MB (ends ~19.1 MB)

    convert_kernel<<<dim3(4, 272), dim3(256), 0, stream>>>(x, Wq, Wk, Wv, Wo, Xb, XT, Wrow, Wtr);
    gram_pr_kernel<<<dim3(16, 6),  dim3(256), 0, stream>>>(XT, Wrow, Wtr, G, P, Rt);
    tm_kernel     <<<dim3(4, 4),   dim3(1024), 0, stream>>>(P, G, Rt, MT);
    final_kernel  <<<dim3(4, 128), dim3(256), 0, stream>>>(Xb, MT, out);
}

// Round 4
// 75.627 us; speedup vs baseline: 1.5973x; 1.5973x over previous
//
#include <hip/hip_runtime.h>

static constexpr int E = 256;
static constexpr int S = 4096;

typedef __attribute__((ext_vector_type(8))) short short8v;   // 8 bf16 (4 VGPRs)
typedef __attribute__((ext_vector_type(4))) float f32x4;     // 4 fp32 acc

static __device__ __forceinline__ unsigned short f2bf(float f) {
    union { float f; unsigned u; } v; v.f = f;
    unsigned r = v.u + 0x7fffu + ((v.u >> 16) & 1u);   // RNE
    return (unsigned short)(r >> 16);
}

static __device__ __forceinline__ f32x4 mfma16(short8v a, short8v b, f32x4 c) {
    return __builtin_amdgcn_mfma_f32_16x16x32_bf16(a, b, c, 0, 0, 0);
}

// 32x32 output tile, 1 wave. out[row,col] = sum_k A[row,k]*B[col,k] (both row-major).
// acc[qr*2+qc]: quadrant rows +qr*16, cols +qc*16.
static __device__ __forceinline__ void gemm_tile32(
    const unsigned short* pa0, const unsigned short* pb0,
    long sA, long sB, int K, f32x4 acc[4])
{
    const unsigned short* pa1 = pa0 + 16 * sA;
    const unsigned short* pb1 = pb0 + 16 * sB;
    #pragma unroll 4
    for (int k = 0; k < K; k += 32) {
        const short8v a0 = *(const short8v*)(pa0 + k);
        const short8v a1 = *(const short8v*)(pa1 + k);
        const short8v b0 = *(const short8v*)(pb0 + k);
        const short8v b1 = *(const short8v*)(pb1 + k);
        acc[0] = mfma16(a0, b0, acc[0]);
        acc[1] = mfma16(a0, b1, acc[1]);
        acc[2] = mfma16(a1, b0, acc[2]);
        acc[3] = mfma16(a1, b1, acc[3]);
    }
}

// ---------------------------------------------------------------------------
// x fp32 -> Xb bf16 [16384][256] and XT bf16 [b][256][4096]  (blockIdx.y<256)
// W* fp32 -> Wrow[wi] bf16 row-major and Wtr[wi] bf16 transposed (y>=256)
__global__ __launch_bounds__(256) void convert_kernel(
    const float* __restrict__ X,
    const float* __restrict__ Wq, const float* __restrict__ Wk,
    const float* __restrict__ Wv, const float* __restrict__ Wo,
    unsigned short* __restrict__ Xb, unsigned short* __restrict__ XT,
    unsigned short* __restrict__ Wrow, unsigned short* __restrict__ Wtr)
{
    __shared__ unsigned short Ls[64][66];
    const int t  = threadIdx.x;
    const int e0 = blockIdx.x * 64;
    const int lr = t >> 2;          // local row
    const int lc = (t & 3) * 16;    // local col segment
    const float* src;
    unsigned short* drow;
    unsigned short* dtr;
    if (blockIdx.y < 256) {
        const int s0 = blockIdx.y * 64;
        src  = X  + (long)(s0 + lr) * E + e0 + lc;
        drow = Xb + (long)(s0 + lr) * E + e0 + lc;
        const int b = s0 >> 12, sl = s0 & 4095;
        dtr = XT + ((long)(b * E + e0 + lr)) * S + sl + lc;
    } else {
        const int wy = blockIdx.y - 256;
        const int wi = wy >> 2, rt = wy & 3;
        const float* W = (wi == 0) ? Wq : (wi == 1) ? Wk : (wi == 2) ? Wv : Wo;
        src  = W + (long)(rt * 64 + lr) * E + e0 + lc;
        drow = Wrow + (long)wi * 65536 + (long)(rt * 64 + lr) * E + e0 + lc;
        dtr  = Wtr  + (long)wi * 65536 + (long)(e0 + lr) * E + rt * 64 + lc;
    }
    short8v v0, v1;
    #pragma unroll
    for (int q = 0; q < 4; ++q) {
        const float4 v = *(const float4*)(src + q * 4);
        const unsigned short b0 = f2bf(v.x), b1 = f2bf(v.y), b2 = f2bf(v.z), b3 = f2bf(v.w);
        Ls[lc + q*4 + 0][lr] = b0; Ls[lc + q*4 + 1][lr] = b1;
        Ls[lc + q*4 + 2][lr] = b2; Ls[lc + q*4 + 3][lr] = b3;
        if (q < 2) { v0[q*4+0]=(short)b0; v0[q*4+1]=(short)b1; v0[q*4+2]=(short)b2; v0[q*4+3]=(short)b3; }
        else { v1[(q-2)*4+0]=(short)b0; v1[(q-2)*4+1]=(short)b1; v1[(q-2)*4+2]=(short)b2; v1[(q-2)*4+3]=(short)b3; }
    }
    *(short8v*)(drow)     = v0;
    *(short8v*)(drow + 8) = v1;
    __syncthreads();
    short8v w0, w1;
    #pragma unroll
    for (int j = 0; j < 8; ++j) { w0[j] = (short)Ls[lr][lc + j]; w1[j] = (short)Ls[lr][lc + 8 + j]; }
    *(short8v*)(dtr)     = w0;
    *(short8v*)(dtr + 8) = w1;
}

// ---------------------------------------------------------------------------
// z<8 : Gp[b][z] = partial x_b^T x_b over s-chunk z (K=512), fp32 out.
// z==8, y==0: P  = Wq^T Wk   (A=WqT, B=WkT), bf16 out
// z==8, y==1: Rt = Wo Wv     (A=Wo row, B=WvT), bf16 out
__global__ __launch_bounds__(256) void gram_pr_kernel(
    const unsigned short* __restrict__ XT, const unsigned short* __restrict__ Wrow,
    const unsigned short* __restrict__ Wtr,
    float* __restrict__ Gp, unsigned short* __restrict__ P,
    unsigned short* __restrict__ Rt)
{
    const int lane = threadIdx.x & 63;
    const int lr = lane & 15, lg = lane >> 4;
    const int w  = blockIdx.x * 4 + (threadIdx.x >> 6);
    const int ti = w >> 3, tj = w & 7;
    const int z  = blockIdx.z;
    f32x4 acc[4] = {};
    if (z < 8) {
        const int b = blockIdx.y;
        const unsigned short* base = XT + (long)b * E * S + z * 512 + lg * 8;
        gemm_tile32(base + (long)(ti * 32 + lr) * S,
                    base + (long)(tj * 32 + lr) * S, S, S, 512, acc);
        float* out = Gp + (((long)b * 8 + z) << 16);
        #pragma unroll
        for (int q = 0; q < 4; ++q) {
            const int qr = q >> 1, qc = q & 1;
            #pragma unroll
            for (int r = 0; r < 4; ++r)
                out[(ti * 32 + qr * 16 + lg * 4 + r) * E + tj * 32 + qc * 16 + lr] = acc[q][r];
        }
    } else {
        const int mode = blockIdx.y;
        if (mode >= 2) return;
        const unsigned short* A = (mode == 0) ? Wtr           : (Wrow + 3 * 65536);
        const unsigned short* B = (mode == 0) ? (Wtr + 65536) : (Wtr + 2 * 65536);
        gemm_tile32(A + (long)(ti * 32 + lr) * E + lg * 8,
                    B + (long)(tj * 32 + lr) * E + lg * 8, E, E, E, acc);
        unsigned short* out = (mode == 0) ? P : Rt;
        #pragma unroll
        for (int q = 0; q < 4; ++q) {
            const int qr = q >> 1, qc = q & 1;
            #pragma unroll
            for (int r = 0; r < 4; ++r)
                out[(ti * 32 + qr * 16 + lg * 4 + r) * E + tj * 32 + qc * 16 + lr] = f2bf(acc[q][r]);
        }
    }
}

// ---------------------------------------------------------------------------
// G[b] bf16 = sum_c Gp[b][c] (8 fp32 chunk partials)
__global__ __launch_bounds__(256) void reduce_g_kernel(
    const float* __restrict__ Gp, unsigned short* __restrict__ G)
{
    const long i = ((long)blockIdx.x * 256 + threadIdx.x) * 4;   // [0, 262144)
    const long b = i >> 16;
    const long off = i & 65535;
    float4 s = make_float4(0.f, 0.f, 0.f, 0.f);
    #pragma unroll
    for (long c = 0; c < 8; ++c) {
        const float4 v = *(const float4*)(Gp + ((b * 8 + c) << 16) + off);
        s.x += v.x; s.y += v.y; s.z += v.z; s.w += v.w;
    }
    ushort4 o;
    o.x = f2bf(s.x); o.y = f2bf(s.y); o.z = f2bf(s.z); o.w = f2bf(s.w);
    *(ushort4*)(G + i) = o;
}

// ---------------------------------------------------------------------------
// Per (band i0, batch b): Tband = P[i0:i0+64,:] @ G_b  -> LDS bf16
// then MT[b][g][i0:i0+64] = 1e-11 * (Rt @ Tband^T)
__global__ __launch_bounds__(1024) void tm_kernel(
    const unsigned short* __restrict__ P, const unsigned short* __restrict__ G,
    const unsigned short* __restrict__ Rt, unsigned short* __restrict__ MT)
{
    __shared__ unsigned short Ts[64][264];
    const int b  = blockIdx.y;
    const int i0 = blockIdx.x * 64;
    const int widx = threadIdx.x >> 6;
    const int lane = threadIdx.x & 63;
    const int lr = lane & 15, lg = lane >> 4;
    {   // stage 1: 2 row-tiles x 8 col-tiles
        const int tr = widx >> 3, tc = widx & 7;
        f32x4 acc[4] = {};
        gemm_tile32(P + (long)(i0 + tr * 32 + lr) * E + lg * 8,
                    G + ((long)b << 16) + (long)(tc * 32 + lr) * E + lg * 8,
                    E, E, E, acc);
        #pragma unroll
        for (int q = 0; q < 4; ++q) {
            const int qr = q >> 1, qc = q & 1;
            #pragma unroll
            for (int r = 0; r < 4; ++r)
                Ts[tr * 32 + qr * 16 + lg * 4 + r][tc * 32 + qc * 16 + lr] = f2bf(acc[q][r]);
        }
    }
    __syncthreads();
    {   // stage 2: 8 g-tiles x 2 e-tiles
        const int tg = widx >> 1, te = widx & 1;
        f32x4 acc[4] = {};
        gemm_tile32(Rt + (long)(tg * 32 + lr) * E + lg * 8,
                    &Ts[te * 32 + lr][lg * 8], E, 264, E, acc);
        unsigned short* out = MT + ((long)b << 16);
        #pragma unroll
        for (int q = 0; q < 4; ++q) {
            const int qr = q >> 1, qc = q & 1;
            #pragma unroll
            for (int r = 0; r < 4; ++r) {
                const int g = tg * 32 + qr * 16 + lg * 4 + r;
                const int e = te * 32 + qc * 16 + lr;
                out[g * E + i0 + e] = f2bf(acc[q][r] * 1e-11f);
            }
        }
    }
}

// ---------------------------------------------------------------------------
// out = Xb @ M_b. 1 wave = 32 rows x 64 cols; block = 4 waves = 128 rows.
__global__ __launch_bounds__(256) void final_kernel(
    const unsigned short* __restrict__ Xb, const unsigned short* __restrict__ MT,
    float* __restrict__ Out)
{
    const int s0 = blockIdx.y * 128 + (threadIdx.x >> 6) * 32;
    const int g0 = blockIdx.x * 64;
    const int b  = s0 >> 12;
    const int lane = threadIdx.x & 63;
    const int lr = lane & 15, lg = lane >> 4;
    const unsigned short* pa0 = Xb + (long)(s0 + lr) * E + lg * 8;
    const unsigned short* pa1 = pa0 + 16 * E;
    const unsigned short* pb  = MT + ((long)b * E + g0 + lr) * E + lg * 8;
    f32x4 acc[2][4] = {};
    #pragma unroll
    for (int k = 0; k < E; k += 32) {
        const short8v a0 = *(const short8v*)(pa0 + k);
        const short8v a1 = *(const short8v*)(pa1 + k);
        #pragma unroll
        for (int ni = 0; ni < 4; ++ni) {
            const short8v bf = *(const short8v*)(pb + (long)ni * 16 * E + k);
            acc[0][ni] = mfma16(a0, bf, acc[0][ni]);
            acc[1][ni] = mfma16(a1, bf, acc[1][ni]);
        }
    }
    #pragma unroll
    for (int mi = 0; mi < 2; ++mi)
        #pragma unroll
        for (int r = 0; r < 4; ++r) {
            float* row = Out + (long)(s0 + mi * 16 + lg * 4 + r) * E + g0 + lr;
            #pragma unroll
            for (int ni = 0; ni < 4; ++ni) row[ni * 16] = acc[mi][ni][r];
        }
}

// ---------------------------------------------------------------------------
extern "C" void kernel_launch(void* const* d_in, const int* in_sizes, int n_in,
                              void* d_out, int out_size, void* d_ws, size_t ws_size,
                              hipStream_t stream)
{
    const float* x  = (const float*)d_in[0];
    const float* Wq = (const float*)d_in[1];
    const float* Wk = (const float*)d_in[2];
    const float* Wv = (const float*)d_in[3];
    const float* Wo = (const float*)d_in[4];
    float* out = (float*)d_out;

    char* ws = (char*)d_ws;
    unsigned short* Xb   = (unsigned short*)(ws);                 //  8.39 MB
    unsigned short* XT   = (unsigned short*)(ws + 8388608);       //  8.39 MB
    unsigned short* Wrow = (unsigned short*)(ws + 16777216);      //  0.52 MB
    unsigned short* Wtr  = (unsigned short*)(ws + 17301504);      //  0.52 MB
    float*          Gp   = (float*)(ws + 17825792);               //  8.39 MB (fp32 partials)
    unsigned short* G    = (unsigned short*)(ws + 26214400);      //  0.52 MB
    unsigned short* P    = (unsigned short*)(ws + 26738688);      //  0.13 MB
    unsigned short* Rt   = (unsigned short*)(ws + 26869760);      //  0.13 MB
    unsigned short* MT   = (unsigned short*)(ws + 27000832);      //  0.52 MB (ends ~27.5 MB)

    convert_kernel <<<dim3(4, 272),   dim3(256),  0, stream>>>(x, Wq, Wk, Wv, Wo, Xb, XT, Wrow, Wtr);
    gram_pr_kernel <<<dim3(16, 4, 9), dim3(256),  0, stream>>>(XT, Wrow, Wtr, Gp, P, Rt);
    reduce_g_kernel<<<dim3(256),      dim3(256),  0, stream>>>(Gp, G);
    tm_kernel      <<<dim3(4, 4),     dim3(1024), 0, stream>>>(P, G, Rt, MT);
    final_kernel   <<<dim3(4, 128),   dim3(256),  0, stream>>>(Xb, MT, out);
}

// Round 5
// 73.591 us; speedup vs baseline: 1.6415x; 1.0277x over previous
//
#include <hip/hip_runtime.h>

static constexpr int E = 256;
static constexpr int S = 4096;

typedef __attribute__((ext_vector_type(8))) short short8v;   // 8 bf16 (4 VGPRs)
typedef __attribute__((ext_vector_type(4))) float f32x4;     // 4 fp32 acc

static __device__ __forceinline__ unsigned short f2bf(float f) {
    union { float f; unsigned u; } v; v.f = f;
    unsigned r = v.u + 0x7fffu + ((v.u >> 16) & 1u);   // RNE
    return (unsigned short)(r >> 16);
}

static __device__ __forceinline__ f32x4 mfma16(short8v a, short8v b, f32x4 c) {
    return __builtin_amdgcn_mfma_f32_16x16x32_bf16(a, b, c, 0, 0, 0);
}

// 32x32 output tile, 1 wave. out[row,col] = sum_k A[row,k]*B[col,k] (both row-major).
// acc[qr*2+qc]: quadrant rows +qr*16, cols +qc*16.
static __device__ __forceinline__ void gemm_tile32(
    const unsigned short* pa0, const unsigned short* pb0,
    long sA, long sB, int K, f32x4 acc[4])
{
    const unsigned short* pa1 = pa0 + 16 * sA;
    const unsigned short* pb1 = pb0 + 16 * sB;
    #pragma unroll 4
    for (int k = 0; k < K; k += 32) {
        const short8v a0 = *(const short8v*)(pa0 + k);
        const short8v a1 = *(const short8v*)(pa1 + k);
        const short8v b0 = *(const short8v*)(pb0 + k);
        const short8v b1 = *(const short8v*)(pb1 + k);
        acc[0] = mfma16(a0, b0, acc[0]);
        acc[1] = mfma16(a0, b1, acc[1]);
        acc[2] = mfma16(a1, b0, acc[2]);
        acc[3] = mfma16(a1, b1, acc[3]);
    }
}

// ---------------------------------------------------------------------------
// x fp32 -> Xb bf16 [16384][256] and XT bf16 [b][256][4096]  (blockIdx.y<256)
// W* fp32 -> Wrow[wi] bf16 row-major and Wtr[wi] bf16 transposed (y>=256)
__global__ __launch_bounds__(256) void convert_kernel(
    const float* __restrict__ X,
    const float* __restrict__ Wq, const float* __restrict__ Wk,
    const float* __restrict__ Wv, const float* __restrict__ Wo,
    unsigned short* __restrict__ Xb, unsigned short* __restrict__ XT,
    unsigned short* __restrict__ Wrow, unsigned short* __restrict__ Wtr)
{
    __shared__ unsigned short Ls[64][66];
    const int t  = threadIdx.x;
    const int e0 = blockIdx.x * 64;
    const int lr = t >> 2;          // local row
    const int lc = (t & 3) * 16;    // local col segment
    const float* src;
    unsigned short* drow;
    unsigned short* dtr;
    if (blockIdx.y < 256) {
        const int s0 = blockIdx.y * 64;
        src  = X  + (long)(s0 + lr) * E + e0 + lc;
        drow = Xb + (long)(s0 + lr) * E + e0 + lc;
        const int b = s0 >> 12, sl = s0 & 4095;
        dtr = XT + ((long)(b * E + e0 + lr)) * S + sl + lc;
    } else {
        const int wy = blockIdx.y - 256;
        const int wi = wy >> 2, rt = wy & 3;
        const float* W = (wi == 0) ? Wq : (wi == 1) ? Wk : (wi == 2) ? Wv : Wo;
        src  = W + (long)(rt * 64 + lr) * E + e0 + lc;
        drow = Wrow + (long)wi * 65536 + (long)(rt * 64 + lr) * E + e0 + lc;
        dtr  = Wtr  + (long)wi * 65536 + (long)(e0 + lr) * E + rt * 64 + lc;
    }
    short8v v0, v1;
    #pragma unroll
    for (int q = 0; q < 4; ++q) {
        const float4 v = *(const float4*)(src + q * 4);
        const unsigned short b0 = f2bf(v.x), b1 = f2bf(v.y), b2 = f2bf(v.z), b3 = f2bf(v.w);
        Ls[lc + q*4 + 0][lr] = b0; Ls[lc + q*4 + 1][lr] = b1;
        Ls[lc + q*4 + 2][lr] = b2; Ls[lc + q*4 + 3][lr] = b3;
        if (q < 2) { v0[q*4+0]=(short)b0; v0[q*4+1]=(short)b1; v0[q*4+2]=(short)b2; v0[q*4+3]=(short)b3; }
        else { v1[(q-2)*4+0]=(short)b0; v1[(q-2)*4+1]=(short)b1; v1[(q-2)*4+2]=(short)b2; v1[(q-2)*4+3]=(short)b3; }
    }
    *(short8v*)(drow)     = v0;
    *(short8v*)(drow + 8) = v1;
    __syncthreads();
    short8v w0, w1;
    #pragma unroll
    for (int j = 0; j < 8; ++j) { w0[j] = (short)Ls[lr][lc + j]; w1[j] = (short)Ls[lr][lc + 8 + j]; }
    *(short8v*)(dtr)     = w0;
    *(short8v*)(dtr + 8) = w1;
}

// ---------------------------------------------------------------------------
// z<8 : Gp[b][z] = partial x_b^T x_b over s-chunk z (K=512), fp32 out.
// z==8, y==0: P  = Wq^T Wk   (A=WqT, B=WkT), bf16 out
// z==8, y==1: Rt = Wo Wv     (A=Wo row, B=WvT), bf16 out
__global__ __launch_bounds__(256) void gram_pr_kernel(
    const unsigned short* __restrict__ XT, const unsigned short* __restrict__ Wrow,
    const unsigned short* __restrict__ Wtr,
    float* __restrict__ Gp, unsigned short* __restrict__ P,
    unsigned short* __restrict__ Rt)
{
    const int lane = threadIdx.x & 63;
    const int lr = lane & 15, lg = lane >> 4;
    const int w  = blockIdx.x * 4 + (threadIdx.x >> 6);
    const int ti = w >> 3, tj = w & 7;
    const int z  = blockIdx.z;
    f32x4 acc[4] = {};
    if (z < 8) {
        const int b = blockIdx.y;
        const unsigned short* base = XT + (long)b * E * S + z * 512 + lg * 8;
        gemm_tile32(base + (long)(ti * 32 + lr) * S,
                    base + (long)(tj * 32 + lr) * S, S, S, 512, acc);
        float* out = Gp + (((long)b * 8 + z) << 16);
        #pragma unroll
        for (int q = 0; q < 4; ++q) {
            const int qr = q >> 1, qc = q & 1;
            #pragma unroll
            for (int r = 0; r < 4; ++r)
                out[(ti * 32 + qr * 16 + lg * 4 + r) * E + tj * 32 + qc * 16 + lr] = acc[q][r];
        }
    } else {
        const int mode = blockIdx.y;
        if (mode >= 2) return;
        const unsigned short* A = (mode == 0) ? Wtr           : (Wrow + 3 * 65536);
        const unsigned short* B = (mode == 0) ? (Wtr + 65536) : (Wtr + 2 * 65536);
        gemm_tile32(A + (long)(ti * 32 + lr) * E + lg * 8,
                    B + (long)(tj * 32 + lr) * E + lg * 8, E, E, E, acc);
        unsigned short* out = (mode == 0) ? P : Rt;
        #pragma unroll
        for (int q = 0; q < 4; ++q) {
            const int qr = q >> 1, qc = q & 1;
            #pragma unroll
            for (int r = 0; r < 4; ++r)
                out[(ti * 32 + qr * 16 + lg * 4 + r) * E + tj * 32 + qc * 16 + lr] = f2bf(acc[q][r]);
        }
    }
}

// ---------------------------------------------------------------------------
// G[b] bf16 = sum_c Gp[b][c] (8 fp32 chunk partials)
__global__ __launch_bounds__(256) void reduce_g_kernel(
    const float* __restrict__ Gp, unsigned short* __restrict__ G)
{
    const long i = ((long)blockIdx.x * 256 + threadIdx.x) * 4;   // [0, 262144)
    const long b = i >> 16;
    const long off = i & 65535;
    float4 s = make_float4(0.f, 0.f, 0.f, 0.f);
    #pragma unroll
    for (long c = 0; c < 8; ++c) {
        const float4 v = *(const float4*)(Gp + ((b * 8 + c) << 16) + off);
        s.x += v.x; s.y += v.y; s.z += v.z; s.w += v.w;
    }
    ushort4 o;
    o.x = f2bf(s.x); o.y = f2bf(s.y); o.z = f2bf(s.z); o.w = f2bf(s.w);
    *(ushort4*)(G + i) = o;
}

// ---------------------------------------------------------------------------
// grid (4 i0-bands, 4 batches, 4 g-slices), 256 threads (4 waves).
// Stage 1 (duplicated across g-slices): Tband = P[i0:i0+64,:] @ G_b -> LDS bf16.
//   wave w: row-tile tr=w>>1, col-tiles tc=(w&1)*4 .. +3.
// Stage 2: MT[b][g0:g0+64][i0:i0+64] = 1e-11 * Rt[g0:,:] @ Tband^T.
//   wave w: tg=w>>1, te=w&1 (one 32x32 tile each).
__global__ __launch_bounds__(256) void tm_kernel(
    const unsigned short* __restrict__ P, const unsigned short* __restrict__ G,
    const unsigned short* __restrict__ Rt, unsigned short* __restrict__ MT)
{
    __shared__ unsigned short Ts[64][264];
    const int b  = blockIdx.y;
    const int i0 = blockIdx.x * 64;
    const int g0 = blockIdx.z * 64;
    const int w    = threadIdx.x >> 6;
    const int lane = threadIdx.x & 63;
    const int lr = lane & 15, lg = lane >> 4;
    {   // stage 1
        const int tr = w >> 1;
        const unsigned short* pa = P + (long)(i0 + tr * 32 + lr) * E + lg * 8;
        #pragma unroll
        for (int j = 0; j < 4; ++j) {
            const int tc = (w & 1) * 4 + j;
            f32x4 acc[4] = {};
            gemm_tile32(pa, G + ((long)b << 16) + (long)(tc * 32 + lr) * E + lg * 8,
                        E, E, E, acc);
            #pragma unroll
            for (int q = 0; q < 4; ++q) {
                const int qr = q >> 1, qc = q & 1;
                #pragma unroll
                for (int r = 0; r < 4; ++r)
                    Ts[tr * 32 + qr * 16 + lg * 4 + r][tc * 32 + qc * 16 + lr] = f2bf(acc[q][r]);
            }
        }
    }
    __syncthreads();
    {   // stage 2
        const int tg = w >> 1, te = w & 1;
        f32x4 acc[4] = {};
        gemm_tile32(Rt + (long)(g0 + tg * 32 + lr) * E + lg * 8,
                    &Ts[te * 32 + lr][lg * 8], E, 264, E, acc);
        unsigned short* out = MT + ((long)b << 16);
        #pragma unroll
        for (int q = 0; q < 4; ++q) {
            const int qr = q >> 1, qc = q & 1;
            #pragma unroll
            for (int r = 0; r < 4; ++r) {
                const int g = g0 + tg * 32 + qr * 16 + lg * 4 + r;
                const int e = te * 32 + qc * 16 + lr;
                out[g * E + i0 + e] = f2bf(acc[q][r] * 1e-11f);
            }
        }
    }
}

// ---------------------------------------------------------------------------
// out = Xb @ M_b. 1 wave = 32 rows x 64 cols; block = 4 waves = 128 rows.
__global__ __launch_bounds__(256) void final_kernel(
    const unsigned short* __restrict__ Xb, const unsigned short* __restrict__ MT,
    float* __restrict__ Out)
{
    const int s0 = blockIdx.y * 128 + (threadIdx.x >> 6) * 32;
    const int g0 = blockIdx.x * 64;
    const int b  = s0 >> 12;
    const int lane = threadIdx.x & 63;
    const int lr = lane & 15, lg = lane >> 4;
    const unsigned short* pa0 = Xb + (long)(s0 + lr) * E + lg * 8;
    const unsigned short* pa1 = pa0 + 16 * E;
    const unsigned short* pb  = MT + ((long)b * E + g0 + lr) * E + lg * 8;
    f32x4 acc[2][4] = {};
    #pragma unroll
    for (int k = 0; k < E; k += 32) {
        const short8v a0 = *(const short8v*)(pa0 + k);
        const short8v a1 = *(const short8v*)(pa1 + k);
        #pragma unroll
        for (int ni = 0; ni < 4; ++ni) {
            const short8v bf = *(const short8v*)(pb + (long)ni * 16 * E + k);
            acc[0][ni] = mfma16(a0, bf, acc[0][ni]);
            acc[1][ni] = mfma16(a1, bf, acc[1][ni]);
        }
    }
    #pragma unroll
    for (int mi = 0; mi < 2; ++mi)
        #pragma unroll
        for (int r = 0; r < 4; ++r) {
            float* row = Out + (long)(s0 + mi * 16 + lg * 4 + r) * E + g0 + lr;
            #pragma unroll
            for (int ni = 0; ni < 4; ++ni) row[ni * 16] = acc[mi][ni][r];
        }
}

// ---------------------------------------------------------------------------
extern "C" void kernel_launch(void* const* d_in, const int* in_sizes, int n_in,
                              void* d_out, int out_size, void* d_ws, size_t ws_size,
                              hipStream_t stream)
{
    const float* x  = (const float*)d_in[0];
    const float* Wq = (const float*)d_in[1];
    const float* Wk = (const float*)d_in[2];
    const float* Wv = (const float*)d_in[3];
    const float* Wo = (const float*)d_in[4];
    float* out = (float*)d_out;

    char* ws = (char*)d_ws;
    unsigned short* Xb   = (unsigned short*)(ws);                 //  8.39 MB
    unsigned short* XT   = (unsigned short*)(ws + 8388608);       //  8.39 MB
    unsigned short* Wrow = (unsigned short*)(ws + 16777216);      //  0.52 MB
    unsigned short* Wtr  = (unsigned short*)(ws + 17301504);      //  0.52 MB
    float*          Gp   = (float*)(ws + 17825792);               //  8.39 MB (fp32 partials)
    unsigned short* G    = (unsigned short*)(ws + 26214400);      //  0.52 MB
    unsigned short* P    = (unsigned short*)(ws + 26738688);      //  0.13 MB
    unsigned short* Rt   = (unsigned short*)(ws + 26869760);      //  0.13 MB
    unsigned short* MT   = (unsigned short*)(ws + 27000832);      //  0.52 MB (ends ~27.5 MB)

    convert_kernel <<<dim3(4, 272),   dim3(256), 0, stream>>>(x, Wq, Wk, Wv, Wo, Xb, XT, Wrow, Wtr);
    gram_pr_kernel <<<dim3(16, 4, 9), dim3(256), 0, stream>>>(XT, Wrow, Wtr, Gp, P, Rt);
    reduce_g_kernel<<<dim3(256),      dim3(256), 0, stream>>>(Gp, G);
    tm_kernel      <<<dim3(4, 4, 4),  dim3(256), 0, stream>>>(P, G, Rt, MT);
    final_kernel   <<<dim3(4, 128),   dim3(256), 0, stream>>>(Xb, MT, out);
}